// Round 17
// baseline (592.863 us; speedup 1.0000x reference)
//
#include <hip/hip_runtime.h>
#include <hip/hip_bf16.h>

// ---------------- Mamba2 block (B=2, L=2048, D_MODEL=2048, D_INNER=4096,
// NH=64, HP=64, DS=128, G=1, DCONV=4, CHUNK=256) ----------------
// Round 17: GEMM BK 64->32 (LDS 128->64KB in-proj, 48KB out-proj) to get
// 2-3 blocks/CU cross-block latency hiding (m114). 64B-row swizzle:
// slot ^= (r&3)^((r>>2)&3) (<=2-way, involution both-sides). vmcnt(4)/(3).
// Same tiles/grids/epilogues. SSM kernels identical to R16.

typedef __attribute__((ext_vector_type(8))) short bf16x8;
typedef __attribute__((ext_vector_type(4))) float f32x4;
typedef __attribute__((ext_vector_type(4))) float float4v;

#define MFMA(a,b,c) __builtin_amdgcn_mfma_f32_16x16x32_bf16((a),(b),(c),0,0,0)

#define GLOAD_LDS16(gp, lp) \
  __builtin_amdgcn_global_load_lds((const __attribute__((address_space(1))) void*)(gp), \
                                   (__attribute__((address_space(3))) void*)(lp), 16, 0, 0)

__device__ __forceinline__ float bf2f(unsigned short u){
  union { unsigned int i; float f; } v; v.i = ((unsigned int)u) << 16; return v.f;
}
__device__ __forceinline__ unsigned short f2bf(float f){
  union { float f; unsigned int i; } v; v.f = f;
  unsigned int x = v.i;
  return (unsigned short)((x + 0x7fffu + ((x >> 16) & 1u)) >> 16);
}

// ---------- f32 -> bf16 (vectorized cast) ----------
__global__ __launch_bounds__(256) void k_f2bf(const float* __restrict__ in,
                                              unsigned short* __restrict__ out, int n){
  int i = (blockIdx.x * 256 + threadIdx.x) * 4;
  if (i >= n) return;
  float4v v = *(const float4v*)(in + i);
  union { unsigned short u[4]; unsigned long long ll; } o;
  o.u[0] = f2bf(v.x); o.u[1] = f2bf(v.y); o.u[2] = f2bf(v.z); o.u[3] = f2bf(v.w);
  *(unsigned long long*)(out + i) = o.ll;
}

// ---------- counted-vmcnt GEMM, BK=32: C[m][n] = sum_k A[m][k]*B[n][k] ----------
// BN=256, 512 threads (8 waves, 2M x 4N). 64B LDS rows; slot swizzle
// s ^= (r&3)^((r>>2)&3). BM=256 (SPLIT=1, 64KB, 2 blk/CU) or BM=128
// (SPLIT=0, 48KB, 3 blk/CU).
template<int BM, int SPLIT>
__global__ __launch_bounds__(512, 2) void k_gcnt(const unsigned short* __restrict__ A,
                                                 const unsigned short* __restrict__ B,
                                                 void* __restrict__ out0,
                                                 void* __restrict__ out1,
                                                 int N, int K){
  constexpr int MI = BM / 32;
  __shared__ unsigned short lds[2 * (BM + 256) * 32];
  int t = threadIdx.x, wid = t >> 6, l = t & 63;
  int wr = wid >> 2, wc = wid & 3;
  int nbx = gridDim.x;
  int bid = blockIdx.y * nbx + blockIdx.x;
  int cpx = (nbx * gridDim.y) >> 3;
  int sbid = (bid & 7) * cpx + (bid >> 3);
  int bx = sbid % nbx, by = sbid / nbx;
  int mbase = by * BM, nbase = bx * 256;

  const unsigned short* Ab = A + (size_t)mbase * K;
  const unsigned short* Bb = B + (size_t)nbase * K;

  f32x4 acc[MI][4];
  #pragma unroll
  for (int i = 0; i < MI; i++)
    #pragma unroll
    for (int j = 0; j < 4; j++) acc[i][j] = (f32x4){0.f,0.f,0.f,0.f};

  // stage one 32-wide K-tile; dest linear, source slot inverse-swizzled
  auto STAGE = [&](int c, int kb){
    char* la = (char*)&lds[c * (BM + 256) * 32];
    char* lb = la + BM * 64;
    #pragma unroll
    for (int q = 0; q < BM / 128; q++){       // A: BM*4 chunks of 16B
      int ch = t + q * 512;
      int r = ch >> 2, s = ch & 3;
      int ss = s ^ (r & 3) ^ ((r >> 2) & 3);
      GLOAD_LDS16(Ab + (size_t)r * K + kb + ss * 8, la + ch * 16);
    }
    #pragma unroll
    for (int q = 0; q < 2; q++){              // B: 1024 chunks of 16B
      int ch = t + q * 512;
      int r = ch >> 2, s = ch & 3;
      int ss = s ^ (r & 3) ^ ((r >> 2) & 3);
      GLOAD_LDS16(Bb + (size_t)r * K + kb + ss * 8, lb + ch * 16);
    }
  };
  auto LD8 = [&](const char* region, int r, int kbyte) -> bf16x8 {
    int addr = r * 64 + (kbyte ^ ((((r & 3) ^ ((r >> 2) & 3))) << 4));
    return *(const bf16x8*)(region + addr);
  };
  auto COMPUTE = [&](int c){
    const char* la = (const char*)&lds[c * (BM + 256) * 32];
    const char* lb = la + BM * 64;
    int kbyte = (l >> 4) << 4;
    bf16x8 af[MI], bfv[4];
    #pragma unroll
    for (int i = 0; i < MI; i++) af[i] = LD8(la, wr * (BM / 2) + i * 16 + (l & 15), kbyte);
    #pragma unroll
    for (int j = 0; j < 4; j++)  bfv[j] = LD8(lb, wc * 64 + j * 16 + (l & 15), kbyte);
    #pragma unroll
    for (int i = 0; i < MI; i++)
      #pragma unroll
      for (int j = 0; j < 4; j++)
        acc[i][j] = MFMA(af[i], bfv[j], acc[i][j]);
  };

  int NT = K >> 5;
  STAGE(0, 0);
  for (int tt = 0; tt < NT; tt++){
    if (tt + 1 < NT){
      STAGE((tt + 1) & 1, (tt + 1) * 32);
      // wait only tile tt's loads; tile tt+1's stay in flight
      if constexpr (BM == 256) asm volatile("s_waitcnt vmcnt(4)" ::: "memory");
      else                     asm volatile("s_waitcnt vmcnt(3)" ::: "memory");
    } else {
      asm volatile("s_waitcnt vmcnt(0)" ::: "memory");
    }
    __builtin_amdgcn_s_barrier();
    COMPUTE(tt & 1);
    asm volatile("s_waitcnt lgkmcnt(0)" ::: "memory");
    __builtin_amdgcn_s_barrier();
  }

  #pragma unroll
  for (int i = 0; i < MI; i++)
    #pragma unroll
    for (int j = 0; j < 4; j++)
      #pragma unroll
      for (int r = 0; r < 4; r++){
        int m = mbase + wr * (BM / 2) + i * 16 + ((l >> 4) << 2) + r;
        int n = nbase + wc * 64 + j * 16 + (l & 15);
        float v = acc[i][j][r];
        if (SPLIT){
          unsigned short bv = f2bf(v);
          if (n < 4096) ((unsigned short*)out0)[(size_t)m * 4096 + n] = bv;
          else          ((unsigned short*)out1)[(size_t)m * 4352 + (n - 4096)] = bv;
        } else {
          ((float*)out0)[(size_t)m * N + n] = v;
        }
      }
}

// ---------- dt GEMM: 64 blocks x 64 rows (precise softplus) ----------
__global__ __launch_bounds__(256) void k_dtg(const unsigned short* __restrict__ A,
                                             const unsigned short* __restrict__ B,
                                             const float* __restrict__ dt_bias,
                                             float* __restrict__ dtw){
  __shared__ unsigned short sA[64 * 64];
  __shared__ unsigned short sB[64 * 64];
  const int K = 2048;
  int t = threadIdx.x, w = t >> 6, l = t & 63;
  int mbase = blockIdx.x * 64;
  const unsigned short* Ab = A + (size_t)mbase * K;
  const unsigned short* Bb = B + 8448ull * K;

  f32x4 acc[4];
  #pragma unroll
  for (int j = 0; j < 4; j++) acc[j] = (f32x4){0.f,0.f,0.f,0.f};

  for (int kb = 0; kb < K; kb += 64){
    #pragma unroll
    for (int q = 0; q < 2; q++){
      int c = t + q * 256;
      GLOAD_LDS16(Ab + (size_t)(c >> 3) * K + kb + (c & 7) * 8, &sA[c * 8]);
      GLOAD_LDS16(Bb + (size_t)(c >> 3) * K + kb + (c & 7) * 8, &sB[c * 8]);
    }
    __syncthreads();
    #pragma unroll
    for (int ks = 0; ks < 64; ks += 32){
      int kk = ks + ((l >> 4) << 3);
      bf16x8 af, bfv[4];
      af = *(const bf16x8*)&sA[(w * 16 + (l & 15)) * 64 + kk];
      #pragma unroll
      for (int j = 0; j < 4; j++) bfv[j] = *(const bf16x8*)&sB[(j * 16 + (l & 15)) * 64 + kk];
      #pragma unroll
      for (int j = 0; j < 4; j++) acc[j] = MFMA(af, bfv[j], acc[j]);
    }
    __syncthreads();
  }
  #pragma unroll
  for (int j = 0; j < 4; j++)
    #pragma unroll
    for (int r = 0; r < 4; r++){
      int m = mbase + w * 16 + ((l >> 4) << 2) + r;
      int h = j * 16 + (l & 15);
      float x = acc[j][r] + dt_bias[h];
      dtw[(size_t)m * 64 + h] = (x > 20.f) ? x : log1pf(expf(x));
    }
}

// ---------- causal depthwise conv (DCONV=4) + bias + silu ----------
__global__ __launch_bounds__(256) void k_conv(const unsigned short* __restrict__ xbc,
                                              const float* __restrict__ cw,
                                              const float* __restrict__ cb,
                                              unsigned short* __restrict__ xc){
  int idx = blockIdx.x * 256 + threadIdx.x;
  int tok = idx / 544;
  int ch0 = (idx - tok * 544) * 8;
  int l = tok & 2047;
  float acc[8];
  #pragma unroll
  for (int e = 0; e < 8; e++) acc[e] = cb[ch0 + e];
  #pragma unroll
  for (int d = 0; d < 4; d++){
    int ll = l - 3 + d;
    if (ll < 0) continue;
    bf16x8 v = *(const bf16x8*)(xbc + (size_t)(tok - 3 + d) * 4352 + ch0);
    #pragma unroll
    for (int e = 0; e < 8; e++)
      acc[e] += bf2f((unsigned short)v[e]) * cw[(ch0 + e) * 4 + d];
  }
  bf16x8 ov;
  #pragma unroll
  for (int e = 0; e < 8; e++){
    float a = acc[e];
    float s = a / (1.f + __expf(-a));
    ov[e] = (short)f2bf(s);
  }
  *(bf16x8*)(xc + (size_t)tok * 4352 + ch0) = ov;
}

// ---------- shfl-based inclusive block scan over 256 values -> sdA[], 2 barriers ----------
__device__ __forceinline__ void blockscan256(float x, float* sdA, float* red,
                                             int t, int w, int l){
  #pragma unroll
  for (int off = 1; off < 64; off <<= 1){
    float u = __shfl_up(x, off, 64);
    if (l >= off) x += u;
  }
  if (l == 63) red[w] = x;
  __syncthreads();
  float pre = 0.f;
  #pragma unroll
  for (int i = 0; i < 3; i++) pre += (i < w) ? red[i] : 0.f;
  sdA[t] = x + pre;
  __syncthreads();
}

// ---------- per-(b,c,h) chunk states: states[p][n] = sum_j w[j] B[j][n] x[j][p] ----------
__global__ __launch_bounds__(256) void k_states(const unsigned short* __restrict__ xc,
                                                const float* __restrict__ dtw,
                                                const float* __restrict__ A_log,
                                                float* __restrict__ states,
                                                float* __restrict__ cdec){
  __shared__ unsigned short sBT[128][152];
  __shared__ unsigned short swxT[64][152];
  __shared__ float sdA[256];
  __shared__ float sdt[256];
  __shared__ float red[4];
  int t = threadIdx.x, w = t >> 6, l = t & 63;
  int h = blockIdx.x & 63, c = (blockIdx.x >> 6) & 7, b = blockIdx.x >> 9;
  int tok0 = b * 2048 + c * 256;

  float dtv = dtw[(size_t)(tok0 + t) * 64 + h];
  float Ah = -__expf(A_log[h]);
  sdt[t] = dtv;
  blockscan256(dtv * Ah, sdA, red, t, w, l);
  float dA_end = sdA[255];
  if (t == 0) cdec[blockIdx.x] = __expf(dA_end);

  f32x4 acc[4][2];
  #pragma unroll
  for (int i = 0; i < 4; i++){ acc[i][0] = (f32x4){0,0,0,0}; acc[i][1] = (f32x4){0,0,0,0}; }

  for (int jh = 0; jh < 2; jh++){
    #pragma unroll
    for (int q = 0; q < 4; q++){
      int idx = q * 256 + t;
      int g = idx >> 6, jp = idx & 63;
      int j = jh * 128 + jp * 2;
      const unsigned short* p0 = xc + (size_t)(tok0 + j) * 4352 + 4096 + g * 8;
      bf16x8 v0 = *(const bf16x8*)p0;
      bf16x8 v1 = *(const bf16x8*)(p0 + 4352);
      #pragma unroll
      for (int e = 0; e < 8; e++){
        unsigned int pk = ((unsigned int)(unsigned short)v1[e] << 16) | (unsigned short)v0[e];
        *(unsigned int*)&sBT[g * 8 + e][jp * 2] = pk;
      }
    }
    #pragma unroll
    for (int q = 0; q < 2; q++){
      int idx = q * 256 + t;
      int g = idx >> 6, jp = idx & 63;
      int j = jh * 128 + jp * 2;
      float w0 = __expf(dA_end - sdA[j])     * sdt[j];
      float w1 = __expf(dA_end - sdA[j + 1]) * sdt[j + 1];
      const unsigned short* p0 = xc + (size_t)(tok0 + j) * 4352 + h * 64 + g * 8;
      bf16x8 v0 = *(const bf16x8*)p0;
      bf16x8 v1 = *(const bf16x8*)(p0 + 4352);
      #pragma unroll
      for (int e = 0; e < 8; e++){
        unsigned int pk = ((unsigned int)f2bf(bf2f((unsigned short)v1[e]) * w1) << 16)
                        |  (unsigned int)f2bf(bf2f((unsigned short)v0[e]) * w0);
        *(unsigned int*)&swxT[g * 8 + e][jp * 2] = pk;
      }
    }
    __syncthreads();
    #pragma unroll
    for (int ks = 0; ks < 4; ks++){
      int kk = ks * 32 + ((l >> 4) << 3);
      bf16x8 afr[4], bfr[2];
      #pragma unroll
      for (int pt = 0; pt < 4; pt++) afr[pt] = *(const bf16x8*)&swxT[pt * 16 + (l & 15)][kk];
      #pragma unroll
      for (int nt = 0; nt < 2; nt++) bfr[nt] = *(const bf16x8*)&sBT[(w * 2 + nt) * 16 + (l & 15)][kk];
      #pragma unroll
      for (int pt = 0; pt < 4; pt++)
        #pragma unroll
        for (int nt = 0; nt < 2; nt++)
          acc[pt][nt] = MFMA(afr[pt], bfr[nt], acc[pt][nt]);
    }
    __syncthreads();
  }
  float* sp = states + (size_t)blockIdx.x * 8192;
  #pragma unroll
  for (int pt = 0; pt < 4; pt++)
    #pragma unroll
    for (int nt = 0; nt < 2; nt++)
      #pragma unroll
      for (int r = 0; r < 4; r++){
        int p = pt * 16 + ((l >> 4) << 2) + r;
        int n = (w * 2 + nt) * 16 + (l & 15);
        sp[p * 128 + n] = acc[pt][nt][r];
      }
}

// ---------- sequential scan over 8 chunks per (b,h,quarter): 512 blocks ----------
__global__ __launch_bounds__(256) void k_scan(const float* __restrict__ states,
                                              const float* __restrict__ cdec,
                                              unsigned short* __restrict__ hprev){
  int q = blockIdx.x & 3, bh = blockIdx.x >> 2;
  int b = bh >> 6, h = bh & 63;
  int t = threadIdx.x;
  float carry[8];
  #pragma unroll
  for (int i = 0; i < 8; i++) carry[i] = 0.f;
  for (int c = 0; c < 8; c++){
    int bch = (b * 8 + c) * 64 + h;
    size_t base = (size_t)bch * 8192 + q * 2048;
    float d = cdec[bch];
    #pragma unroll
    for (int i = 0; i < 8; i++){
      int e = t + i * 256;
      hprev[base + e] = f2bf(carry[i]);
      carry[i] = carry[i] * d + states[base + e];
    }
  }
}

// ---------- per-(b,c,h): y = (scores@x) + (C*expf)@h_prev^T + Dp*x ----------
__global__ __launch_bounds__(256) void k_y(const unsigned short* __restrict__ xc,
                                           const float* __restrict__ dtw,
                                           const float* __restrict__ A_log,
                                           const unsigned short* __restrict__ hprev,
                                           const float* __restrict__ Dp,
                                           unsigned short* __restrict__ y){
  __shared__ unsigned short sxT[64][280];
  __shared__ unsigned short sS[4][32][40];
  __shared__ float sdA[256];
  __shared__ float sdt[256];
  __shared__ float red[4];
  int t = threadIdx.x, w = t >> 6, l = t & 63;
  int h = blockIdx.x & 63, c = (blockIdx.x >> 6) & 7, b = blockIdx.x >> 9;
  int tok0 = b * 2048 + c * 256;

  float dtv = dtw[(size_t)(tok0 + t) * 64 + h];
  float Ah = -__expf(A_log[h]);
  sdt[t] = dtv;
  blockscan256(dtv * Ah, sdA, red, t, w, l);

  #pragma unroll
  for (int q = 0; q < 4; q++){
    int idx = q * 256 + t;
    int g = idx >> 7, jp = idx & 127;
    int j = jp * 2;
    const unsigned short* p0 = xc + (size_t)(tok0 + j) * 4352 + h * 64 + g * 8;
    bf16x8 v0 = *(const bf16x8*)p0;
    bf16x8 v1 = *(const bf16x8*)(p0 + 4352);
    #pragma unroll
    for (int e = 0; e < 8; e++){
      unsigned int pk = ((unsigned int)(unsigned short)v1[e] << 16) | (unsigned short)v0[e];
      *(unsigned int*)&sxT[g * 8 + e][jp * 2] = pk;
    }
  }
  __syncthreads();

  int ibh[2]; ibh[0] = 32 * w; ibh[1] = 224 - 32 * w;
  int njt[2]; njt[0] = w + 1;  njt[1] = 8 - w;

  bf16x8 cfr[2][2][4];
  #pragma unroll
  for (int hf = 0; hf < 2; hf++)
    #pragma unroll
    for (int it = 0; it < 2; it++)
      #pragma unroll
      for (int kn = 0; kn < 4; kn++){
        int i = ibh[hf] + it * 16 + (l & 15);
        int n = kn * 32 + ((l >> 4) << 3);
        cfr[hf][it][kn] = *(const bf16x8*)(xc + (size_t)(tok0 + i) * 4352 + 4224 + n);
      }

  f32x4 acc[2][2][4];
  #pragma unroll
  for (int hf = 0; hf < 2; hf++)
    #pragma unroll
    for (int i = 0; i < 2; i++)
      #pragma unroll
      for (int j = 0; j < 4; j++) acc[hf][i][j] = (f32x4){0,0,0,0};

  #pragma unroll
  for (int hf = 0; hf < 2; hf++){
    int ib = ibh[hf];
    for (int jt = 0; jt < njt[hf]; jt++){
      f32x4 cb[2][2];
      #pragma unroll
      for (int i = 0; i < 2; i++){ cb[i][0] = (f32x4){0,0,0,0}; cb[i][1] = (f32x4){0,0,0,0}; }
      #pragma unroll
      for (int kn = 0; kn < 4; kn++){
        bf16x8 bfr[2];
        #pragma unroll
        for (int js = 0; js < 2; js++){
          int j = jt * 32 + js * 16 + (l & 15);
          int n = kn * 32 + ((l >> 4) << 3);
          bfr[js] = *(const bf16x8*)(xc + (size_t)(tok0 + j) * 4352 + 4096 + n);
        }
        #pragma unroll
        for (int it = 0; it < 2; it++)
          #pragma unroll
          for (int js = 0; js < 2; js++)
            cb[it][js] = MFMA(cfr[hf][it][kn], bfr[js], cb[it][js]);
      }
      #pragma unroll
      for (int it = 0; it < 2; it++)
        #pragma unroll
        for (int js = 0; js < 2; js++)
          #pragma unroll
          for (int r = 0; r < 4; r++){
            int il = it * 16 + ((l >> 4) << 2) + r;
            int i = ib + il;
            int j = jt * 32 + js * 16 + (l & 15);
            float v = (i >= j) ? cb[it][js][r] * __expf(sdA[i] - sdA[j]) * sdt[j] : 0.f;
            sS[w][il][js * 16 + (l & 15)] = f2bf(v);
          }
      int kk = ((l >> 4) << 3);
      bf16x8 sfr[2], xfr[4];
      #pragma unroll
      for (int it = 0; it < 2; it++) sfr[it] = *(const bf16x8*)&sS[w][it * 16 + (l & 15)][kk];
      #pragma unroll
      for (int pt = 0; pt < 4; pt++) xfr[pt] = *(const bf16x8*)&sxT[pt * 16 + (l & 15)][jt * 32 + kk];
      #pragma unroll
      for (int it = 0; it < 2; it++)
        #pragma unroll
        for (int pt = 0; pt < 4; pt++)
          acc[hf][it][pt] = MFMA(sfr[it], xfr[pt], acc[hf][it][pt]);
    }
  }

  const unsigned short* hp = hprev + (size_t)blockIdx.x * 8192;
  float esc[2][2];
  #pragma unroll
  for (int hf = 0; hf < 2; hf++)
    #pragma unroll
    for (int it = 0; it < 2; it++)
      esc[hf][it] = __expf(sdA[ibh[hf] + it * 16 + (l & 15)]);
  #pragma unroll
  for (int kn = 0; kn < 4; kn++){
    bf16x8 hfr[4];
    #pragma unroll
    for (int pt = 0; pt < 4; pt++){
      int p = pt * 16 + (l & 15);
      int n = kn * 32 + ((l >> 4) << 3);
      hfr[pt] = *(const bf16x8*)(hp + p * 128 + n);
    }
    #pragma unroll
    for (int hf = 0; hf < 2; hf++)
      #pragma unroll
      for (int it = 0; it < 2; it++){
        bf16x8 afv;
        #pragma unroll
        for (int e = 0; e < 8; e++)
          afv[e] = (short)f2bf(bf2f((unsigned short)cfr[hf][it][kn][e]) * esc[hf][it]);
        #pragma unroll
        for (int pt = 0; pt < 4; pt++)
          acc[hf][it][pt] = MFMA(afv, hfr[pt], acc[hf][it][pt]);
      }
  }

  float dph = Dp[h];
  #pragma unroll
  for (int hf = 0; hf < 2; hf++)
    #pragma unroll
    for (int it = 0; it < 2; it++)
      #pragma unroll
      for (int pt = 0; pt < 4; pt++)
        #pragma unroll
        for (int r = 0; r < 4; r++){
          int i = ibh[hf] + it * 16 + ((l >> 4) << 2) + r;
          int p = pt * 16 + (l & 15);
          float xv = bf2f(sxT[p][i]);
          float v = acc[hf][it][pt][r] + dph * xv;
          y[(size_t)(tok0 + i) * 4096 + h * 64 + p] = f2bf(v);
        }
}

// ---------- gate with silu(z), RMS-norm, * norm_w -> bf16 ----------
__global__ __launch_bounds__(256) void k_norm(const unsigned short* __restrict__ y,
                                              const unsigned short* __restrict__ zbuf,
                                              const float* __restrict__ norm_w,
                                              unsigned short* __restrict__ yn){
  int tok = blockIdx.x, t = threadIdx.x, w = t >> 6, l = t & 63;
  float vals[16];
  float ss = 0.f;
  #pragma unroll
  for (int q = 0; q < 2; q++){
    int col = q * 2048 + t * 8;
    bf16x8 yv = *(const bf16x8*)(y    + (size_t)tok * 4096 + col);
    bf16x8 zv = *(const bf16x8*)(zbuf + (size_t)tok * 4096 + col);
    #pragma unroll
    for (int e = 0; e < 8; e++){
      float yy = bf2f((unsigned short)yv[e]);
      float zz = bf2f((unsigned short)zv[e]);
      float g = yy * (zz / (1.f + __expf(-zz)));
      vals[q * 8 + e] = g;
      ss += g * g;
    }
  }
  #pragma unroll
  for (int off = 32; off >= 1; off >>= 1) ss += __shfl_xor(ss, off, 64);
  __shared__ float red[4];
  if (l == 0) red[w] = ss;
  __syncthreads();
  float total = red[0] + red[1] + red[2] + red[3];
  float scale = rsqrtf(total * (1.f / 4096.f) + 1e-5f);
  #pragma unroll
  for (int q = 0; q < 2; q++){
    int col = q * 2048 + t * 8;
    bf16x8 ov;
    #pragma unroll
    for (int e = 0; e < 8; e++) ov[e] = (short)f2bf(vals[q * 8 + e] * scale * norm_w[col + e]);
    *(bf16x8*)(yn + (size_t)tok * 4096 + col) = ov;
  }
}

extern "C" void kernel_launch(void* const* d_in, const int* in_sizes, int n_in,
                              void* d_out, int out_size, void* d_ws, size_t ws_size,
                              hipStream_t stream) {
  const float* u       = (const float*)d_in[0];
  const float* W_in    = (const float*)d_in[1];
  const float* conv_w  = (const float*)d_in[2];
  const float* conv_b  = (const float*)d_in[3];
  const float* dt_bias = (const float*)d_in[4];
  const float* A_log   = (const float*)d_in[5];
  const float* Dp      = (const float*)d_in[6];
  const float* norm_w  = (const float*)d_in[7];
  const float* W_out   = (const float*)d_in[8];

  char* ws = (char*)d_ws;
  size_t off = 0;
  auto nxt = [&](size_t bytes) -> char* {
    char* r = ws + off;
    off += (bytes + 255) & ~(size_t)255;
    return r;
  };
  char* RZ = nxt(4096ull * 4096 * 2);   // zbuf -> wout_bf
  char* RX = nxt(4096ull * 4352 * 2);   // xbc -> states(f32) -> ybuf
  char* RC = nxt(4096ull * 4352 * 2);   // win_bf -> xc -> ynbuf
  char* RH = nxt(1024ull * 8192 * 2);   // u_bf -> hprev
  float* dtw  = (float*)nxt(4096ull * 64 * 4);
  float* cdec = (float*)nxt(1024ull * 4);
  size_t need = off;
  (void)in_sizes; (void)n_in; (void)out_size;
  if (ws_size < need) return;

  unsigned short* zbuf    = (unsigned short*)RZ;
  unsigned short* wout_bf = (unsigned short*)RZ;   // after k_norm
  unsigned short* xbc     = (unsigned short*)RX;
  float*          states  = (float*)RX;
  unsigned short* ybuf    = (unsigned short*)RX;
  unsigned short* win_bf  = (unsigned short*)RC;
  unsigned short* xc      = (unsigned short*)RC;
  unsigned short* ynbuf   = (unsigned short*)RC;
  unsigned short* u_bf    = (unsigned short*)RH;
  unsigned short* hprev   = (unsigned short*)RH;

  k_f2bf<<<8192,  256, 0, stream>>>(u,    u_bf,   4096 * 2048);
  k_f2bf<<<17024, 256, 0, stream>>>(W_in, win_bf, 8512 * 2048);
  k_dtg<<<64, 256, 0, stream>>>(u_bf, win_bf, dt_bias, dtw);
  // in-proj: M=4096, N=8448, K=2048; 256x256 tiles BK=32, grid 33x16
  k_gcnt<256,1><<<dim3(33, 16), 512, 0, stream>>>(u_bf, win_bf, zbuf, xbc, 8448, 2048);
  k_conv<<<8704, 256, 0, stream>>>(xbc, conv_w, conv_b, xc);
  k_states<<<1024, 256, 0, stream>>>(xc, dtw, A_log, states, cdec);
  k_scan<<<512, 256, 0, stream>>>(states, cdec, hprev);
  k_y<<<1024, 256, 0, stream>>>(xc, dtw, A_log, hprev, Dp, ybuf);
  k_norm<<<4096, 256, 0, stream>>>(ybuf, zbuf, norm_w, ynbuf);
  k_f2bf<<<8192, 256, 0, stream>>>(W_out, wout_bf, 2048 * 4096);
  // out-proj: M=4096, N=2048, K=4096; 128x256 tiles BK=32, grid 8x32
  k_gcnt<128,0><<<dim3(8, 32), 512, 0, stream>>>(ynbuf, wout_bf, d_out, nullptr, 2048, 4096);
}

// Round 18
// 564.142 us; speedup vs baseline: 1.0509x; 1.0509x over previous
//
#include <hip/hip_runtime.h>
#include <hip/hip_bf16.h>

// ---------------- Mamba2 block (B=2, L=2048, D_MODEL=2048, D_INNER=4096,
// NH=64, HP=64, DS=128, G=1, DCONV=4, CHUNK=256) ----------------
// Round 18: exact revert to R16 (best-known 563.8us). R17's BK=32 regressed
// (occupancy didn't improve, weaker swizzle reintroduced 1.3e7 conflicts).
// Config: 2-phase counted-vmcnt GEMMs (BM=256 in-proj / BM=128 out-proj,
// BK=64, T2 3-bit swizzle, XCD swizzle), SSM with j-pair staging + balanced
// k_y + shfl blockscan + __expf.

typedef __attribute__((ext_vector_type(8))) short bf16x8;
typedef __attribute__((ext_vector_type(4))) float f32x4;
typedef __attribute__((ext_vector_type(4))) float float4v;

#define MFMA(a,b,c) __builtin_amdgcn_mfma_f32_16x16x32_bf16((a),(b),(c),0,0,0)

#define GLOAD_LDS16(gp, lp) \
  __builtin_amdgcn_global_load_lds((const __attribute__((address_space(1))) void*)(gp), \
                                   (__attribute__((address_space(3))) void*)(lp), 16, 0, 0)

__device__ __forceinline__ float bf2f(unsigned short u){
  union { unsigned int i; float f; } v; v.i = ((unsigned int)u) << 16; return v.f;
}
__device__ __forceinline__ unsigned short f2bf(float f){
  union { float f; unsigned int i; } v; v.f = f;
  unsigned int x = v.i;
  return (unsigned short)((x + 0x7fffu + ((x >> 16) & 1u)) >> 16);
}

// ---------- f32 -> bf16 (vectorized cast) ----------
__global__ __launch_bounds__(256) void k_f2bf(const float* __restrict__ in,
                                              unsigned short* __restrict__ out, int n){
  int i = (blockIdx.x * 256 + threadIdx.x) * 4;
  if (i >= n) return;
  float4v v = *(const float4v*)(in + i);
  union { unsigned short u[4]; unsigned long long ll; } o;
  o.u[0] = f2bf(v.x); o.u[1] = f2bf(v.y); o.u[2] = f2bf(v.z); o.u[3] = f2bf(v.w);
  *(unsigned long long*)(out + i) = o.ll;
}

// ---------- counted-vmcnt GEMM: C[m][n] = sum_k A[m][k]*B[n][k] ----------
template<int BM, int SPLIT>
__global__ __launch_bounds__(512, 2) void k_gcnt(const unsigned short* __restrict__ A,
                                                 const unsigned short* __restrict__ B,
                                                 void* __restrict__ out0,
                                                 void* __restrict__ out1,
                                                 int N, int K){
  constexpr int MI = BM / 32;
  __shared__ unsigned short lds[2 * (BM + 256) * 64];
  int t = threadIdx.x, wid = t >> 6, l = t & 63;
  int wr = wid >> 2, wc = wid & 3;
  int nbx = gridDim.x;
  int bid = blockIdx.y * nbx + blockIdx.x;
  int cpx = (nbx * gridDim.y) >> 3;
  int sbid = (bid & 7) * cpx + (bid >> 3);
  int bx = sbid % nbx, by = sbid / nbx;
  int mbase = by * BM, nbase = bx * 256;

  const unsigned short* Ab = A + (size_t)mbase * K;
  const unsigned short* Bb = B + (size_t)nbase * K;

  f32x4 acc[MI][4];
  #pragma unroll
  for (int i = 0; i < MI; i++)
    #pragma unroll
    for (int j = 0; j < 4; j++) acc[i][j] = (f32x4){0.f,0.f,0.f,0.f};

  auto STAGE = [&](int c, int kb){
    char* la = (char*)&lds[c * (BM + 256) * 64];
    char* lb = la + BM * 128;
    #pragma unroll
    for (int q = 0; q < BM / 64; q++){
      int o = (t + q * 512) * 16;
      int bs = o ^ (((o >> 7) & 7) << 4);
      int r = bs >> 7, cb = bs & 127;
      GLOAD_LDS16((const char*)Ab + (size_t)r * (K * 2) + (size_t)kb * 2 + cb, la + o);
    }
    #pragma unroll
    for (int q = 0; q < 4; q++){
      int o = (t + q * 512) * 16;
      int bs = o ^ (((o >> 7) & 7) << 4);
      int r = bs >> 7, cb = bs & 127;
      GLOAD_LDS16((const char*)Bb + (size_t)r * (K * 2) + (size_t)kb * 2 + cb, lb + o);
    }
  };
  auto LD8 = [&](const char* region, int r, int kbyte) -> bf16x8 {
    int addr = r * 128 + (kbyte ^ ((r & 7) << 4));
    return *(const bf16x8*)(region + addr);
  };
  auto COMPUTE = [&](int c){
    const char* la = (const char*)&lds[c * (BM + 256) * 64];
    const char* lb = la + BM * 128;
    #pragma unroll
    for (int ks = 0; ks < 64; ks += 32){
      int kbyte = ks * 2 + ((l >> 4) << 4);
      bf16x8 af[MI], bfv[4];
      #pragma unroll
      for (int i = 0; i < MI; i++) af[i] = LD8(la, wr * (BM / 2) + i * 16 + (l & 15), kbyte);
      #pragma unroll
      for (int j = 0; j < 4; j++)  bfv[j] = LD8(lb, wc * 64 + j * 16 + (l & 15), kbyte);
      #pragma unroll
      for (int i = 0; i < MI; i++)
        #pragma unroll
        for (int j = 0; j < 4; j++)
          acc[i][j] = MFMA(af[i], bfv[j], acc[i][j]);
    }
  };

  int NT = K >> 6;
  STAGE(0, 0);
  for (int tt = 0; tt < NT; tt++){
    if (tt + 1 < NT){
      STAGE((tt + 1) & 1, (tt + 1) * 64);
      if constexpr (BM == 256) asm volatile("s_waitcnt vmcnt(8)" ::: "memory");
      else                     asm volatile("s_waitcnt vmcnt(6)" ::: "memory");
    } else {
      asm volatile("s_waitcnt vmcnt(0)" ::: "memory");
    }
    __builtin_amdgcn_s_barrier();
    COMPUTE(tt & 1);
    asm volatile("s_waitcnt lgkmcnt(0)" ::: "memory");
    __builtin_amdgcn_s_barrier();
  }

  #pragma unroll
  for (int i = 0; i < MI; i++)
    #pragma unroll
    for (int j = 0; j < 4; j++)
      #pragma unroll
      for (int r = 0; r < 4; r++){
        int m = mbase + wr * (BM / 2) + i * 16 + ((l >> 4) << 2) + r;
        int n = nbase + wc * 64 + j * 16 + (l & 15);
        float v = acc[i][j][r];
        if (SPLIT){
          unsigned short bv = f2bf(v);
          if (n < 4096) ((unsigned short*)out0)[(size_t)m * 4096 + n] = bv;
          else          ((unsigned short*)out1)[(size_t)m * 4352 + (n - 4096)] = bv;
        } else {
          ((float*)out0)[(size_t)m * N + n] = v;
        }
      }
}

// ---------- dt GEMM: 64 blocks x 64 rows (precise softplus) ----------
__global__ __launch_bounds__(256) void k_dtg(const unsigned short* __restrict__ A,
                                             const unsigned short* __restrict__ B,
                                             const float* __restrict__ dt_bias,
                                             float* __restrict__ dtw){
  __shared__ unsigned short sA[64 * 64];
  __shared__ unsigned short sB[64 * 64];
  const int K = 2048;
  int t = threadIdx.x, w = t >> 6, l = t & 63;
  int mbase = blockIdx.x * 64;
  const unsigned short* Ab = A + (size_t)mbase * K;
  const unsigned short* Bb = B + 8448ull * K;

  f32x4 acc[4];
  #pragma unroll
  for (int j = 0; j < 4; j++) acc[j] = (f32x4){0.f,0.f,0.f,0.f};

  for (int kb = 0; kb < K; kb += 64){
    #pragma unroll
    for (int q = 0; q < 2; q++){
      int c = t + q * 256;
      GLOAD_LDS16(Ab + (size_t)(c >> 3) * K + kb + (c & 7) * 8, &sA[c * 8]);
      GLOAD_LDS16(Bb + (size_t)(c >> 3) * K + kb + (c & 7) * 8, &sB[c * 8]);
    }
    __syncthreads();
    #pragma unroll
    for (int ks = 0; ks < 64; ks += 32){
      int kk = ks + ((l >> 4) << 3);
      bf16x8 af, bfv[4];
      af = *(const bf16x8*)&sA[(w * 16 + (l & 15)) * 64 + kk];
      #pragma unroll
      for (int j = 0; j < 4; j++) bfv[j] = *(const bf16x8*)&sB[(j * 16 + (l & 15)) * 64 + kk];
      #pragma unroll
      for (int j = 0; j < 4; j++) acc[j] = MFMA(af, bfv[j], acc[j]);
    }
    __syncthreads();
  }
  #pragma unroll
  for (int j = 0; j < 4; j++)
    #pragma unroll
    for (int r = 0; r < 4; r++){
      int m = mbase + w * 16 + ((l >> 4) << 2) + r;
      int h = j * 16 + (l & 15);
      float x = acc[j][r] + dt_bias[h];
      dtw[(size_t)m * 64 + h] = (x > 20.f) ? x : log1pf(expf(x));
    }
}

// ---------- causal depthwise conv (DCONV=4) + bias + silu ----------
__global__ __launch_bounds__(256) void k_conv(const unsigned short* __restrict__ xbc,
                                              const float* __restrict__ cw,
                                              const float* __restrict__ cb,
                                              unsigned short* __restrict__ xc){
  int idx = blockIdx.x * 256 + threadIdx.x;
  int tok = idx / 544;
  int ch0 = (idx - tok * 544) * 8;
  int l = tok & 2047;
  float acc[8];
  #pragma unroll
  for (int e = 0; e < 8; e++) acc[e] = cb[ch0 + e];
  #pragma unroll
  for (int d = 0; d < 4; d++){
    int ll = l - 3 + d;
    if (ll < 0) continue;
    bf16x8 v = *(const bf16x8*)(xbc + (size_t)(tok - 3 + d) * 4352 + ch0);
    #pragma unroll
    for (int e = 0; e < 8; e++)
      acc[e] += bf2f((unsigned short)v[e]) * cw[(ch0 + e) * 4 + d];
  }
  bf16x8 ov;
  #pragma unroll
  for (int e = 0; e < 8; e++){
    float a = acc[e];
    float s = a / (1.f + __expf(-a));
    ov[e] = (short)f2bf(s);
  }
  *(bf16x8*)(xc + (size_t)tok * 4352 + ch0) = ov;
}

// ---------- shfl-based inclusive block scan over 256 values -> sdA[], 2 barriers ----------
__device__ __forceinline__ void blockscan256(float x, float* sdA, float* red,
                                             int t, int w, int l){
  #pragma unroll
  for (int off = 1; off < 64; off <<= 1){
    float u = __shfl_up(x, off, 64);
    if (l >= off) x += u;
  }
  if (l == 63) red[w] = x;
  __syncthreads();
  float pre = 0.f;
  #pragma unroll
  for (int i = 0; i < 3; i++) pre += (i < w) ? red[i] : 0.f;
  sdA[t] = x + pre;
  __syncthreads();
}

// ---------- per-(b,c,h) chunk states: states[p][n] = sum_j w[j] B[j][n] x[j][p] ----------
// Staging: j-pair u32 writes, lane=j-pair -> conflict-free; pad 152 (16B rows).
__global__ __launch_bounds__(256) void k_states(const unsigned short* __restrict__ xc,
                                                const float* __restrict__ dtw,
                                                const float* __restrict__ A_log,
                                                float* __restrict__ states,
                                                float* __restrict__ cdec){
  __shared__ unsigned short sBT[128][152];
  __shared__ unsigned short swxT[64][152];
  __shared__ float sdA[256];
  __shared__ float sdt[256];
  __shared__ float red[4];
  int t = threadIdx.x, w = t >> 6, l = t & 63;
  int h = blockIdx.x & 63, c = (blockIdx.x >> 6) & 7, b = blockIdx.x >> 9;
  int tok0 = b * 2048 + c * 256;

  float dtv = dtw[(size_t)(tok0 + t) * 64 + h];
  float Ah = -__expf(A_log[h]);
  sdt[t] = dtv;
  blockscan256(dtv * Ah, sdA, red, t, w, l);
  float dA_end = sdA[255];
  if (t == 0) cdec[blockIdx.x] = __expf(dA_end);

  f32x4 acc[4][2];
  #pragma unroll
  for (int i = 0; i < 4; i++){ acc[i][0] = (f32x4){0,0,0,0}; acc[i][1] = (f32x4){0,0,0,0}; }

  for (int jh = 0; jh < 2; jh++){
    #pragma unroll
    for (int q = 0; q < 4; q++){
      int idx = q * 256 + t;
      int g = idx >> 6, jp = idx & 63;
      int j = jh * 128 + jp * 2;
      const unsigned short* p0 = xc + (size_t)(tok0 + j) * 4352 + 4096 + g * 8;
      bf16x8 v0 = *(const bf16x8*)p0;
      bf16x8 v1 = *(const bf16x8*)(p0 + 4352);
      #pragma unroll
      for (int e = 0; e < 8; e++){
        unsigned int pk = ((unsigned int)(unsigned short)v1[e] << 16) | (unsigned short)v0[e];
        *(unsigned int*)&sBT[g * 8 + e][jp * 2] = pk;
      }
    }
    #pragma unroll
    for (int q = 0; q < 2; q++){
      int idx = q * 256 + t;
      int g = idx >> 6, jp = idx & 63;
      int j = jh * 128 + jp * 2;
      float w0 = __expf(dA_end - sdA[j])     * sdt[j];
      float w1 = __expf(dA_end - sdA[j + 1]) * sdt[j + 1];
      const unsigned short* p0 = xc + (size_t)(tok0 + j) * 4352 + h * 64 + g * 8;
      bf16x8 v0 = *(const bf16x8*)p0;
      bf16x8 v1 = *(const bf16x8*)(p0 + 4352);
      #pragma unroll
      for (int e = 0; e < 8; e++){
        unsigned int pk = ((unsigned int)f2bf(bf2f((unsigned short)v1[e]) * w1) << 16)
                        |  (unsigned int)f2bf(bf2f((unsigned short)v0[e]) * w0);
        *(unsigned int*)&swxT[g * 8 + e][jp * 2] = pk;
      }
    }
    __syncthreads();
    #pragma unroll
    for (int ks = 0; ks < 4; ks++){
      int kk = ks * 32 + ((l >> 4) << 3);
      bf16x8 afr[4], bfr[2];
      #pragma unroll
      for (int pt = 0; pt < 4; pt++) afr[pt] = *(const bf16x8*)&swxT[pt * 16 + (l & 15)][kk];
      #pragma unroll
      for (int nt = 0; nt < 2; nt++) bfr[nt] = *(const bf16x8*)&sBT[(w * 2 + nt) * 16 + (l & 15)][kk];
      #pragma unroll
      for (int pt = 0; pt < 4; pt++)
        #pragma unroll
        for (int nt = 0; nt < 2; nt++)
          acc[pt][nt] = MFMA(afr[pt], bfr[nt], acc[pt][nt]);
    }
    __syncthreads();
  }
  float* sp = states + (size_t)blockIdx.x * 8192;
  #pragma unroll
  for (int pt = 0; pt < 4; pt++)
    #pragma unroll
    for (int nt = 0; nt < 2; nt++)
      #pragma unroll
      for (int r = 0; r < 4; r++){
        int p = pt * 16 + ((l >> 4) << 2) + r;
        int n = (w * 2 + nt) * 16 + (l & 15);
        sp[p * 128 + n] = acc[pt][nt][r];
      }
}

// ---------- sequential scan over 8 chunks per (b,h,quarter): 512 blocks ----------
__global__ __launch_bounds__(256) void k_scan(const float* __restrict__ states,
                                              const float* __restrict__ cdec,
                                              unsigned short* __restrict__ hprev){
  int q = blockIdx.x & 3, bh = blockIdx.x >> 2;
  int b = bh >> 6, h = bh & 63;
  int t = threadIdx.x;
  float carry[8];
  #pragma unroll
  for (int i = 0; i < 8; i++) carry[i] = 0.f;
  for (int c = 0; c < 8; c++){
    int bch = (b * 8 + c) * 64 + h;
    size_t base = (size_t)bch * 8192 + q * 2048;
    float d = cdec[bch];
    #pragma unroll
    for (int i = 0; i < 8; i++){
      int e = t + i * 256;
      hprev[base + e] = f2bf(carry[i]);
      carry[i] = carry[i] * d + states[base + e];
    }
  }
}

// ---------- per-(b,c,h): y = (scores@x) + (C*expf)@h_prev^T + Dp*x ----------
// Balanced waves; sxT j-pair staging (pad 280, conflict-free writes).
__global__ __launch_bounds__(256) void k_y(const unsigned short* __restrict__ xc,
                                           const float* __restrict__ dtw,
                                           const float* __restrict__ A_log,
                                           const unsigned short* __restrict__ hprev,
                                           const float* __restrict__ Dp,
                                           unsigned short* __restrict__ y){
  __shared__ unsigned short sxT[64][280];
  __shared__ unsigned short sS[4][32][40];
  __shared__ float sdA[256];
  __shared__ float sdt[256];
  __shared__ float red[4];
  int t = threadIdx.x, w = t >> 6, l = t & 63;
  int h = blockIdx.x & 63, c = (blockIdx.x >> 6) & 7, b = blockIdx.x >> 9;
  int tok0 = b * 2048 + c * 256;

  float dtv = dtw[(size_t)(tok0 + t) * 64 + h];
  float Ah = -__expf(A_log[h]);
  sdt[t] = dtv;
  blockscan256(dtv * Ah, sdA, red, t, w, l);

  #pragma unroll
  for (int q = 0; q < 4; q++){
    int idx = q * 256 + t;
    int g = idx >> 7, jp = idx & 127;
    int j = jp * 2;
    const unsigned short* p0 = xc + (size_t)(tok0 + j) * 4352 + h * 64 + g * 8;
    bf16x8 v0 = *(const bf16x8*)p0;
    bf16x8 v1 = *(const bf16x8*)(p0 + 4352);
    #pragma unroll
    for (int e = 0; e < 8; e++){
      unsigned int pk = ((unsigned int)(unsigned short)v1[e] << 16) | (unsigned short)v0[e];
      *(unsigned int*)&sxT[g * 8 + e][jp * 2] = pk;
    }
  }
  __syncthreads();

  int ibh[2]; ibh[0] = 32 * w; ibh[1] = 224 - 32 * w;
  int njt[2]; njt[0] = w + 1;  njt[1] = 8 - w;

  bf16x8 cfr[2][2][4];
  #pragma unroll
  for (int hf = 0; hf < 2; hf++)
    #pragma unroll
    for (int it = 0; it < 2; it++)
      #pragma unroll
      for (int kn = 0; kn < 4; kn++){
        int i = ibh[hf] + it * 16 + (l & 15);
        int n = kn * 32 + ((l >> 4) << 3);
        cfr[hf][it][kn] = *(const bf16x8*)(xc + (size_t)(tok0 + i) * 4352 + 4224 + n);
      }

  f32x4 acc[2][2][4];
  #pragma unroll
  for (int hf = 0; hf < 2; hf++)
    #pragma unroll
    for (int i = 0; i < 2; i++)
      #pragma unroll
      for (int j = 0; j < 4; j++) acc[hf][i][j] = (f32x4){0,0,0,0};

  #pragma unroll
  for (int hf = 0; hf < 2; hf++){
    int ib = ibh[hf];
    for (int jt = 0; jt < njt[hf]; jt++){
      f32x4 cb[2][2];
      #pragma unroll
      for (int i = 0; i < 2; i++){ cb[i][0] = (f32x4){0,0,0,0}; cb[i][1] = (f32x4){0,0,0,0}; }
      #pragma unroll
      for (int kn = 0; kn < 4; kn++){
        bf16x8 bfr[2];
        #pragma unroll
        for (int js = 0; js < 2; js++){
          int j = jt * 32 + js * 16 + (l & 15);
          int n = kn * 32 + ((l >> 4) << 3);
          bfr[js] = *(const bf16x8*)(xc + (size_t)(tok0 + j) * 4352 + 4096 + n);
        }
        #pragma unroll
        for (int it = 0; it < 2; it++)
          #pragma unroll
          for (int js = 0; js < 2; js++)
            cb[it][js] = MFMA(cfr[hf][it][kn], bfr[js], cb[it][js]);
      }
      #pragma unroll
      for (int it = 0; it < 2; it++)
        #pragma unroll
        for (int js = 0; js < 2; js++)
          #pragma unroll
          for (int r = 0; r < 4; r++){
            int il = it * 16 + ((l >> 4) << 2) + r;
            int i = ib + il;
            int j = jt * 32 + js * 16 + (l & 15);
            float v = (i >= j) ? cb[it][js][r] * __expf(sdA[i] - sdA[j]) * sdt[j] : 0.f;
            sS[w][il][js * 16 + (l & 15)] = f2bf(v);
          }
      int kk = ((l >> 4) << 3);
      bf16x8 sfr[2], xfr[4];
      #pragma unroll
      for (int it = 0; it < 2; it++) sfr[it] = *(const bf16x8*)&sS[w][it * 16 + (l & 15)][kk];
      #pragma unroll
      for (int pt = 0; pt < 4; pt++) xfr[pt] = *(const bf16x8*)&sxT[pt * 16 + (l & 15)][jt * 32 + kk];
      #pragma unroll
      for (int it = 0; it < 2; it++)
        #pragma unroll
        for (int pt = 0; pt < 4; pt++)
          acc[hf][it][pt] = MFMA(sfr[it], xfr[pt], acc[hf][it][pt]);
    }
  }

  const unsigned short* hp = hprev + (size_t)blockIdx.x * 8192;
  float esc[2][2];
  #pragma unroll
  for (int hf = 0; hf < 2; hf++)
    #pragma unroll
    for (int it = 0; it < 2; it++)
      esc[hf][it] = __expf(sdA[ibh[hf] + it * 16 + (l & 15)]);
  #pragma unroll
  for (int kn = 0; kn < 4; kn++){
    bf16x8 hfr[4];
    #pragma unroll
    for (int pt = 0; pt < 4; pt++){
      int p = pt * 16 + (l & 15);
      int n = kn * 32 + ((l >> 4) << 3);
      hfr[pt] = *(const bf16x8*)(hp + p * 128 + n);
    }
    #pragma unroll
    for (int hf = 0; hf < 2; hf++)
      #pragma unroll
      for (int it = 0; it < 2; it++){
        bf16x8 afv;
        #pragma unroll
        for (int e = 0; e < 8; e++)
          afv[e] = (short)f2bf(bf2f((unsigned short)cfr[hf][it][kn][e]) * esc[hf][it]);
        #pragma unroll
        for (int pt = 0; pt < 4; pt++)
          acc[hf][it][pt] = MFMA(afv, hfr[pt], acc[hf][it][pt]);
      }
  }

  float dph = Dp[h];
  #pragma unroll
  for (int hf = 0; hf < 2; hf++)
    #pragma unroll
    for (int it = 0; it < 2; it++)
      #pragma unroll
      for (int pt = 0; pt < 4; pt++)
        #pragma unroll
        for (int r = 0; r < 4; r++){
          int i = ibh[hf] + it * 16 + ((l >> 4) << 2) + r;
          int p = pt * 16 + (l & 15);
          float xv = bf2f(sxT[p][i]);
          float v = acc[hf][it][pt][r] + dph * xv;
          y[(size_t)(tok0 + i) * 4096 + h * 64 + p] = f2bf(v);
        }
}

// ---------- gate with silu(z), RMS-norm, * norm_w -> bf16 ----------
__global__ __launch_bounds__(256) void k_norm(const unsigned short* __restrict__ y,
                                              const unsigned short* __restrict__ zbuf,
                                              const float* __restrict__ norm_w,
                                              unsigned short* __restrict__ yn){
  int tok = blockIdx.x, t = threadIdx.x, w = t >> 6, l = t & 63;
  float vals[16];
  float ss = 0.f;
  #pragma unroll
  for (int q = 0; q < 2; q++){
    int col = q * 2048 + t * 8;
    bf16x8 yv = *(const bf16x8*)(y    + (size_t)tok * 4096 + col);
    bf16x8 zv = *(const bf16x8*)(zbuf + (size_t)tok * 4096 + col);
    #pragma unroll
    for (int e = 0; e < 8; e++){
      float yy = bf2f((unsigned short)yv[e]);
      float zz = bf2f((unsigned short)zv[e]);
      float g = yy * (zz / (1.f + __expf(-zz)));
      vals[q * 8 + e] = g;
      ss += g * g;
    }
  }
  #pragma unroll
  for (int off = 32; off >= 1; off >>= 1) ss += __shfl_xor(ss, off, 64);
  __shared__ float red[4];
  if (l == 0) red[w] = ss;
  __syncthreads();
  float total = red[0] + red[1] + red[2] + red[3];
  float scale = rsqrtf(total * (1.f / 4096.f) + 1e-5f);
  #pragma unroll
  for (int q = 0; q < 2; q++){
    int col = q * 2048 + t * 8;
    bf16x8 ov;
    #pragma unroll
    for (int e = 0; e < 8; e++) ov[e] = (short)f2bf(vals[q * 8 + e] * scale * norm_w[col + e]);
    *(bf16x8*)(yn + (size_t)tok * 4096 + col) = ov;
  }
}

extern "C" void kernel_launch(void* const* d_in, const int* in_sizes, int n_in,
                              void* d_out, int out_size, void* d_ws, size_t ws_size,
                              hipStream_t stream) {
  const float* u       = (const float*)d_in[0];
  const float* W_in    = (const float*)d_in[1];
  const float* conv_w  = (const float*)d_in[2];
  const float* conv_b  = (const float*)d_in[3];
  const float* dt_bias = (const float*)d_in[4];
  const float* A_log   = (const float*)d_in[5];
  const float* Dp      = (const float*)d_in[6];
  const float* norm_w  = (const float*)d_in[7];
  const float* W_out   = (const float*)d_in[8];

  char* ws = (char*)d_ws;
  size_t off = 0;
  auto nxt = [&](size_t bytes) -> char* {
    char* r = ws + off;
    off += (bytes + 255) & ~(size_t)255;
    return r;
  };
  char* RZ = nxt(4096ull * 4096 * 2);   // zbuf -> wout_bf
  char* RX = nxt(4096ull * 4352 * 2);   // xbc -> states(f32) -> ybuf
  char* RC = nxt(4096ull * 4352 * 2);   // win_bf -> xc -> ynbuf
  char* RH = nxt(1024ull * 8192 * 2);   // u_bf -> hprev
  float* dtw  = (float*)nxt(4096ull * 64 * 4);
  float* cdec = (float*)nxt(1024ull * 4);
  size_t need = off;
  (void)in_sizes; (void)n_in; (void)out_size;
  if (ws_size < need) return;

  unsigned short* zbuf    = (unsigned short*)RZ;
  unsigned short* wout_bf = (unsigned short*)RZ;   // after k_norm
  unsigned short* xbc     = (unsigned short*)RX;
  float*          states  = (float*)RX;
  unsigned short* ybuf    = (unsigned short*)RX;
  unsigned short* win_bf  = (unsigned short*)RC;
  unsigned short* xc      = (unsigned short*)RC;
  unsigned short* ynbuf   = (unsigned short*)RC;
  unsigned short* u_bf    = (unsigned short*)RH;
  unsigned short* hprev   = (unsigned short*)RH;

  k_f2bf<<<8192,  256, 0, stream>>>(u,    u_bf,   4096 * 2048);
  k_f2bf<<<17024, 256, 0, stream>>>(W_in, win_bf, 8512 * 2048);
  k_dtg<<<64, 256, 0, stream>>>(u_bf, win_bf, dt_bias, dtw);
  // in-proj: M=4096, N=8448, K=2048; 256x256 tiles, grid 33x16
  k_gcnt<256,1><<<dim3(33, 16), 512, 0, stream>>>(u_bf, win_bf, zbuf, xbc, 8448, 2048);
  k_conv<<<8704, 256, 0, stream>>>(xbc, conv_w, conv_b, xc);
  k_states<<<1024, 256, 0, stream>>>(xc, dtw, A_log, states, cdec);
  k_scan<<<512, 256, 0, stream>>>(states, cdec, hprev);
  k_y<<<1024, 256, 0, stream>>>(xc, dtw, A_log, hprev, Dp, ybuf);
  k_norm<<<4096, 256, 0, stream>>>(ybuf, zbuf, norm_w, ynbuf);
  k_f2bf<<<8192, 256, 0, stream>>>(W_out, wout_bf, 2048 * 4096);
  // out-proj: M=4096, N=2048, K=4096; 128x256 tiles, grid 8x32 (256 blocks)
  k_gcnt<128,0><<<dim3(8, 32), 512, 0, stream>>>(ynbuf, wout_bf, d_out, nullptr, 2048, 4096);
}

// Round 19
// 563.187 us; speedup vs baseline: 1.0527x; 1.0017x over previous
//
#include <hip/hip_runtime.h>
#include <hip/hip_bf16.h>

// ---------------- Mamba2 block (B=2, L=2048, D_MODEL=2048, D_INNER=4096,
// NH=64, HP=64, DS=128, G=1, DCONV=4, CHUNK=256) ----------------
// Round 19 (final): best-known configuration, identical to R16/R18 (563.8 /
// 564.1 us). 2-phase counted-vmcnt GEMMs (BM=256 in-proj / BM=128 out-proj,
// BK=64, T2 3-bit swizzle both-sides, bijective XCD swizzle, conflict-free),
// SSM: j-pair staging, balanced k_y waves, shfl blockscan, __expf.

typedef __attribute__((ext_vector_type(8))) short bf16x8;
typedef __attribute__((ext_vector_type(4))) float f32x4;
typedef __attribute__((ext_vector_type(4))) float float4v;

#define MFMA(a,b,c) __builtin_amdgcn_mfma_f32_16x16x32_bf16((a),(b),(c),0,0,0)

#define GLOAD_LDS16(gp, lp) \
  __builtin_amdgcn_global_load_lds((const __attribute__((address_space(1))) void*)(gp), \
                                   (__attribute__((address_space(3))) void*)(lp), 16, 0, 0)

__device__ __forceinline__ float bf2f(unsigned short u){
  union { unsigned int i; float f; } v; v.i = ((unsigned int)u) << 16; return v.f;
}
__device__ __forceinline__ unsigned short f2bf(float f){
  union { float f; unsigned int i; } v; v.f = f;
  unsigned int x = v.i;
  return (unsigned short)((x + 0x7fffu + ((x >> 16) & 1u)) >> 16);
}

// ---------- f32 -> bf16 (vectorized cast) ----------
__global__ __launch_bounds__(256) void k_f2bf(const float* __restrict__ in,
                                              unsigned short* __restrict__ out, int n){
  int i = (blockIdx.x * 256 + threadIdx.x) * 4;
  if (i >= n) return;
  float4v v = *(const float4v*)(in + i);
  union { unsigned short u[4]; unsigned long long ll; } o;
  o.u[0] = f2bf(v.x); o.u[1] = f2bf(v.y); o.u[2] = f2bf(v.z); o.u[3] = f2bf(v.w);
  *(unsigned long long*)(out + i) = o.ll;
}

// ---------- counted-vmcnt GEMM: C[m][n] = sum_k A[m][k]*B[n][k] ----------
template<int BM, int SPLIT>
__global__ __launch_bounds__(512, 2) void k_gcnt(const unsigned short* __restrict__ A,
                                                 const unsigned short* __restrict__ B,
                                                 void* __restrict__ out0,
                                                 void* __restrict__ out1,
                                                 int N, int K){
  constexpr int MI = BM / 32;
  __shared__ unsigned short lds[2 * (BM + 256) * 64];
  int t = threadIdx.x, wid = t >> 6, l = t & 63;
  int wr = wid >> 2, wc = wid & 3;
  int nbx = gridDim.x;
  int bid = blockIdx.y * nbx + blockIdx.x;
  int cpx = (nbx * gridDim.y) >> 3;
  int sbid = (bid & 7) * cpx + (bid >> 3);
  int bx = sbid % nbx, by = sbid / nbx;
  int mbase = by * BM, nbase = bx * 256;

  const unsigned short* Ab = A + (size_t)mbase * K;
  const unsigned short* Bb = B + (size_t)nbase * K;

  f32x4 acc[MI][4];
  #pragma unroll
  for (int i = 0; i < MI; i++)
    #pragma unroll
    for (int j = 0; j < 4; j++) acc[i][j] = (f32x4){0.f,0.f,0.f,0.f};

  auto STAGE = [&](int c, int kb){
    char* la = (char*)&lds[c * (BM + 256) * 64];
    char* lb = la + BM * 128;
    #pragma unroll
    for (int q = 0; q < BM / 64; q++){
      int o = (t + q * 512) * 16;
      int bs = o ^ (((o >> 7) & 7) << 4);
      int r = bs >> 7, cb = bs & 127;
      GLOAD_LDS16((const char*)Ab + (size_t)r * (K * 2) + (size_t)kb * 2 + cb, la + o);
    }
    #pragma unroll
    for (int q = 0; q < 4; q++){
      int o = (t + q * 512) * 16;
      int bs = o ^ (((o >> 7) & 7) << 4);
      int r = bs >> 7, cb = bs & 127;
      GLOAD_LDS16((const char*)Bb + (size_t)r * (K * 2) + (size_t)kb * 2 + cb, lb + o);
    }
  };
  auto LD8 = [&](const char* region, int r, int kbyte) -> bf16x8 {
    int addr = r * 128 + (kbyte ^ ((r & 7) << 4));
    return *(const bf16x8*)(region + addr);
  };
  auto COMPUTE = [&](int c){
    const char* la = (const char*)&lds[c * (BM + 256) * 64];
    const char* lb = la + BM * 128;
    #pragma unroll
    for (int ks = 0; ks < 64; ks += 32){
      int kbyte = ks * 2 + ((l >> 4) << 4);
      bf16x8 af[MI], bfv[4];
      #pragma unroll
      for (int i = 0; i < MI; i++) af[i] = LD8(la, wr * (BM / 2) + i * 16 + (l & 15), kbyte);
      #pragma unroll
      for (int j = 0; j < 4; j++)  bfv[j] = LD8(lb, wc * 64 + j * 16 + (l & 15), kbyte);
      #pragma unroll
      for (int i = 0; i < MI; i++)
        #pragma unroll
        for (int j = 0; j < 4; j++)
          acc[i][j] = MFMA(af[i], bfv[j], acc[i][j]);
    }
  };

  int NT = K >> 6;
  STAGE(0, 0);
  for (int tt = 0; tt < NT; tt++){
    if (tt + 1 < NT){
      STAGE((tt + 1) & 1, (tt + 1) * 64);
      if constexpr (BM == 256) asm volatile("s_waitcnt vmcnt(8)" ::: "memory");
      else                     asm volatile("s_waitcnt vmcnt(6)" ::: "memory");
    } else {
      asm volatile("s_waitcnt vmcnt(0)" ::: "memory");
    }
    __builtin_amdgcn_s_barrier();
    COMPUTE(tt & 1);
    asm volatile("s_waitcnt lgkmcnt(0)" ::: "memory");
    __builtin_amdgcn_s_barrier();
  }

  #pragma unroll
  for (int i = 0; i < MI; i++)
    #pragma unroll
    for (int j = 0; j < 4; j++)
      #pragma unroll
      for (int r = 0; r < 4; r++){
        int m = mbase + wr * (BM / 2) + i * 16 + ((l >> 4) << 2) + r;
        int n = nbase + wc * 64 + j * 16 + (l & 15);
        float v = acc[i][j][r];
        if (SPLIT){
          unsigned short bv = f2bf(v);
          if (n < 4096) ((unsigned short*)out0)[(size_t)m * 4096 + n] = bv;
          else          ((unsigned short*)out1)[(size_t)m * 4352 + (n - 4096)] = bv;
        } else {
          ((float*)out0)[(size_t)m * N + n] = v;
        }
      }
}

// ---------- dt GEMM: 64 blocks x 64 rows (precise softplus) ----------
__global__ __launch_bounds__(256) void k_dtg(const unsigned short* __restrict__ A,
                                             const unsigned short* __restrict__ B,
                                             const float* __restrict__ dt_bias,
                                             float* __restrict__ dtw){
  __shared__ unsigned short sA[64 * 64];
  __shared__ unsigned short sB[64 * 64];
  const int K = 2048;
  int t = threadIdx.x, w = t >> 6, l = t & 63;
  int mbase = blockIdx.x * 64;
  const unsigned short* Ab = A + (size_t)mbase * K;
  const unsigned short* Bb = B + 8448ull * K;

  f32x4 acc[4];
  #pragma unroll
  for (int j = 0; j < 4; j++) acc[j] = (f32x4){0.f,0.f,0.f,0.f};

  for (int kb = 0; kb < K; kb += 64){
    #pragma unroll
    for (int q = 0; q < 2; q++){
      int c = t + q * 256;
      GLOAD_LDS16(Ab + (size_t)(c >> 3) * K + kb + (c & 7) * 8, &sA[c * 8]);
      GLOAD_LDS16(Bb + (size_t)(c >> 3) * K + kb + (c & 7) * 8, &sB[c * 8]);
    }
    __syncthreads();
    #pragma unroll
    for (int ks = 0; ks < 64; ks += 32){
      int kk = ks + ((l >> 4) << 3);
      bf16x8 af, bfv[4];
      af = *(const bf16x8*)&sA[(w * 16 + (l & 15)) * 64 + kk];
      #pragma unroll
      for (int j = 0; j < 4; j++) bfv[j] = *(const bf16x8*)&sB[(j * 16 + (l & 15)) * 64 + kk];
      #pragma unroll
      for (int j = 0; j < 4; j++) acc[j] = MFMA(af, bfv[j], acc[j]);
    }
    __syncthreads();
  }
  #pragma unroll
  for (int j = 0; j < 4; j++)
    #pragma unroll
    for (int r = 0; r < 4; r++){
      int m = mbase + w * 16 + ((l >> 4) << 2) + r;
      int h = j * 16 + (l & 15);
      float x = acc[j][r] + dt_bias[h];
      dtw[(size_t)m * 64 + h] = (x > 20.f) ? x : log1pf(expf(x));
    }
}

// ---------- causal depthwise conv (DCONV=4) + bias + silu ----------
__global__ __launch_bounds__(256) void k_conv(const unsigned short* __restrict__ xbc,
                                              const float* __restrict__ cw,
                                              const float* __restrict__ cb,
                                              unsigned short* __restrict__ xc){
  int idx = blockIdx.x * 256 + threadIdx.x;
  int tok = idx / 544;
  int ch0 = (idx - tok * 544) * 8;
  int l = tok & 2047;
  float acc[8];
  #pragma unroll
  for (int e = 0; e < 8; e++) acc[e] = cb[ch0 + e];
  #pragma unroll
  for (int d = 0; d < 4; d++){
    int ll = l - 3 + d;
    if (ll < 0) continue;
    bf16x8 v = *(const bf16x8*)(xbc + (size_t)(tok - 3 + d) * 4352 + ch0);
    #pragma unroll
    for (int e = 0; e < 8; e++)
      acc[e] += bf2f((unsigned short)v[e]) * cw[(ch0 + e) * 4 + d];
  }
  bf16x8 ov;
  #pragma unroll
  for (int e = 0; e < 8; e++){
    float a = acc[e];
    float s = a / (1.f + __expf(-a));
    ov[e] = (short)f2bf(s);
  }
  *(bf16x8*)(xc + (size_t)tok * 4352 + ch0) = ov;
}

// ---------- shfl-based inclusive block scan over 256 values -> sdA[], 2 barriers ----------
__device__ __forceinline__ void blockscan256(float x, float* sdA, float* red,
                                             int t, int w, int l){
  #pragma unroll
  for (int off = 1; off < 64; off <<= 1){
    float u = __shfl_up(x, off, 64);
    if (l >= off) x += u;
  }
  if (l == 63) red[w] = x;
  __syncthreads();
  float pre = 0.f;
  #pragma unroll
  for (int i = 0; i < 3; i++) pre += (i < w) ? red[i] : 0.f;
  sdA[t] = x + pre;
  __syncthreads();
}

// ---------- per-(b,c,h) chunk states: states[p][n] = sum_j w[j] B[j][n] x[j][p] ----------
// Staging: j-pair u32 writes, lane=j-pair -> conflict-free; pad 152 (16B rows).
__global__ __launch_bounds__(256) void k_states(const unsigned short* __restrict__ xc,
                                                const float* __restrict__ dtw,
                                                const float* __restrict__ A_log,
                                                float* __restrict__ states,
                                                float* __restrict__ cdec){
  __shared__ unsigned short sBT[128][152];
  __shared__ unsigned short swxT[64][152];
  __shared__ float sdA[256];
  __shared__ float sdt[256];
  __shared__ float red[4];
  int t = threadIdx.x, w = t >> 6, l = t & 63;
  int h = blockIdx.x & 63, c = (blockIdx.x >> 6) & 7, b = blockIdx.x >> 9;
  int tok0 = b * 2048 + c * 256;

  float dtv = dtw[(size_t)(tok0 + t) * 64 + h];
  float Ah = -__expf(A_log[h]);
  sdt[t] = dtv;
  blockscan256(dtv * Ah, sdA, red, t, w, l);
  float dA_end = sdA[255];
  if (t == 0) cdec[blockIdx.x] = __expf(dA_end);

  f32x4 acc[4][2];
  #pragma unroll
  for (int i = 0; i < 4; i++){ acc[i][0] = (f32x4){0,0,0,0}; acc[i][1] = (f32x4){0,0,0,0}; }

  for (int jh = 0; jh < 2; jh++){
    #pragma unroll
    for (int q = 0; q < 4; q++){
      int idx = q * 256 + t;
      int g = idx >> 6, jp = idx & 63;
      int j = jh * 128 + jp * 2;
      const unsigned short* p0 = xc + (size_t)(tok0 + j) * 4352 + 4096 + g * 8;
      bf16x8 v0 = *(const bf16x8*)p0;
      bf16x8 v1 = *(const bf16x8*)(p0 + 4352);
      #pragma unroll
      for (int e = 0; e < 8; e++){
        unsigned int pk = ((unsigned int)(unsigned short)v1[e] << 16) | (unsigned short)v0[e];
        *(unsigned int*)&sBT[g * 8 + e][jp * 2] = pk;
      }
    }
    #pragma unroll
    for (int q = 0; q < 2; q++){
      int idx = q * 256 + t;
      int g = idx >> 6, jp = idx & 63;
      int j = jh * 128 + jp * 2;
      float w0 = __expf(dA_end - sdA[j])     * sdt[j];
      float w1 = __expf(dA_end - sdA[j + 1]) * sdt[j + 1];
      const unsigned short* p0 = xc + (size_t)(tok0 + j) * 4352 + h * 64 + g * 8;
      bf16x8 v0 = *(const bf16x8*)p0;
      bf16x8 v1 = *(const bf16x8*)(p0 + 4352);
      #pragma unroll
      for (int e = 0; e < 8; e++){
        unsigned int pk = ((unsigned int)f2bf(bf2f((unsigned short)v1[e]) * w1) << 16)
                        |  (unsigned int)f2bf(bf2f((unsigned short)v0[e]) * w0);
        *(unsigned int*)&swxT[g * 8 + e][jp * 2] = pk;
      }
    }
    __syncthreads();
    #pragma unroll
    for (int ks = 0; ks < 4; ks++){
      int kk = ks * 32 + ((l >> 4) << 3);
      bf16x8 afr[4], bfr[2];
      #pragma unroll
      for (int pt = 0; pt < 4; pt++) afr[pt] = *(const bf16x8*)&swxT[pt * 16 + (l & 15)][kk];
      #pragma unroll
      for (int nt = 0; nt < 2; nt++) bfr[nt] = *(const bf16x8*)&sBT[(w * 2 + nt) * 16 + (l & 15)][kk];
      #pragma unroll
      for (int pt = 0; pt < 4; pt++)
        #pragma unroll
        for (int nt = 0; nt < 2; nt++)
          acc[pt][nt] = MFMA(afr[pt], bfr[nt], acc[pt][nt]);
    }
    __syncthreads();
  }
  float* sp = states + (size_t)blockIdx.x * 8192;
  #pragma unroll
  for (int pt = 0; pt < 4; pt++)
    #pragma unroll
    for (int nt = 0; nt < 2; nt++)
      #pragma unroll
      for (int r = 0; r < 4; r++){
        int p = pt * 16 + ((l >> 4) << 2) + r;
        int n = (w * 2 + nt) * 16 + (l & 15);
        sp[p * 128 + n] = acc[pt][nt][r];
      }
}

// ---------- sequential scan over 8 chunks per (b,h,quarter): 512 blocks ----------
__global__ __launch_bounds__(256) void k_scan(const float* __restrict__ states,
                                              const float* __restrict__ cdec,
                                              unsigned short* __restrict__ hprev){
  int q = blockIdx.x & 3, bh = blockIdx.x >> 2;
  int b = bh >> 6, h = bh & 63;
  int t = threadIdx.x;
  float carry[8];
  #pragma unroll
  for (int i = 0; i < 8; i++) carry[i] = 0.f;
  for (int c = 0; c < 8; c++){
    int bch = (b * 8 + c) * 64 + h;
    size_t base = (size_t)bch * 8192 + q * 2048;
    float d = cdec[bch];
    #pragma unroll
    for (int i = 0; i < 8; i++){
      int e = t + i * 256;
      hprev[base + e] = f2bf(carry[i]);
      carry[i] = carry[i] * d + states[base + e];
    }
  }
}

// ---------- per-(b,c,h): y = (scores@x) + (C*expf)@h_prev^T + Dp*x ----------
// Balanced waves; sxT j-pair staging (pad 280, conflict-free writes).
__global__ __launch_bounds__(256) void k_y(const unsigned short* __restrict__ xc,
                                           const float* __restrict__ dtw,
                                           const float* __restrict__ A_log,
                                           const unsigned short* __restrict__ hprev,
                                           const float* __restrict__ Dp,
                                           unsigned short* __restrict__ y){
  __shared__ unsigned short sxT[64][280];
  __shared__ unsigned short sS[4][32][40];
  __shared__ float sdA[256];
  __shared__ float sdt[256];
  __shared__ float red[4];
  int t = threadIdx.x, w = t >> 6, l = t & 63;
  int h = blockIdx.x & 63, c = (blockIdx.x >> 6) & 7, b = blockIdx.x >> 9;
  int tok0 = b * 2048 + c * 256;

  float dtv = dtw[(size_t)(tok0 + t) * 64 + h];
  float Ah = -__expf(A_log[h]);
  sdt[t] = dtv;
  blockscan256(dtv * Ah, sdA, red, t, w, l);

  #pragma unroll
  for (int q = 0; q < 4; q++){
    int idx = q * 256 + t;
    int g = idx >> 7, jp = idx & 127;
    int j = jp * 2;
    const unsigned short* p0 = xc + (size_t)(tok0 + j) * 4352 + h * 64 + g * 8;
    bf16x8 v0 = *(const bf16x8*)p0;
    bf16x8 v1 = *(const bf16x8*)(p0 + 4352);
    #pragma unroll
    for (int e = 0; e < 8; e++){
      unsigned int pk = ((unsigned int)(unsigned short)v1[e] << 16) | (unsigned short)v0[e];
      *(unsigned int*)&sxT[g * 8 + e][jp * 2] = pk;
    }
  }
  __syncthreads();

  int ibh[2]; ibh[0] = 32 * w; ibh[1] = 224 - 32 * w;
  int njt[2]; njt[0] = w + 1;  njt[1] = 8 - w;

  bf16x8 cfr[2][2][4];
  #pragma unroll
  for (int hf = 0; hf < 2; hf++)
    #pragma unroll
    for (int it = 0; it < 2; it++)
      #pragma unroll
      for (int kn = 0; kn < 4; kn++){
        int i = ibh[hf] + it * 16 + (l & 15);
        int n = kn * 32 + ((l >> 4) << 3);
        cfr[hf][it][kn] = *(const bf16x8*)(xc + (size_t)(tok0 + i) * 4352 + 4224 + n);
      }

  f32x4 acc[2][2][4];
  #pragma unroll
  for (int hf = 0; hf < 2; hf++)
    #pragma unroll
    for (int i = 0; i < 2; i++)
      #pragma unroll
      for (int j = 0; j < 4; j++) acc[hf][i][j] = (f32x4){0,0,0,0};

  #pragma unroll
  for (int hf = 0; hf < 2; hf++){
    int ib = ibh[hf];
    for (int jt = 0; jt < njt[hf]; jt++){
      f32x4 cb[2][2];
      #pragma unroll
      for (int i = 0; i < 2; i++){ cb[i][0] = (f32x4){0,0,0,0}; cb[i][1] = (f32x4){0,0,0,0}; }
      #pragma unroll
      for (int kn = 0; kn < 4; kn++){
        bf16x8 bfr[2];
        #pragma unroll
        for (int js = 0; js < 2; js++){
          int j = jt * 32 + js * 16 + (l & 15);
          int n = kn * 32 + ((l >> 4) << 3);
          bfr[js] = *(const bf16x8*)(xc + (size_t)(tok0 + j) * 4352 + 4096 + n);
        }
        #pragma unroll
        for (int it = 0; it < 2; it++)
          #pragma unroll
          for (int js = 0; js < 2; js++)
            cb[it][js] = MFMA(cfr[hf][it][kn], bfr[js], cb[it][js]);
      }
      #pragma unroll
      for (int it = 0; it < 2; it++)
        #pragma unroll
        for (int js = 0; js < 2; js++)
          #pragma unroll
          for (int r = 0; r < 4; r++){
            int il = it * 16 + ((l >> 4) << 2) + r;
            int i = ib + il;
            int j = jt * 32 + js * 16 + (l & 15);
            float v = (i >= j) ? cb[it][js][r] * __expf(sdA[i] - sdA[j]) * sdt[j] : 0.f;
            sS[w][il][js * 16 + (l & 15)] = f2bf(v);
          }
      int kk = ((l >> 4) << 3);
      bf16x8 sfr[2], xfr[4];
      #pragma unroll
      for (int it = 0; it < 2; it++) sfr[it] = *(const bf16x8*)&sS[w][it * 16 + (l & 15)][kk];
      #pragma unroll
      for (int pt = 0; pt < 4; pt++) xfr[pt] = *(const bf16x8*)&sxT[pt * 16 + (l & 15)][jt * 32 + kk];
      #pragma unroll
      for (int it = 0; it < 2; it++)
        #pragma unroll
        for (int pt = 0; pt < 4; pt++)
          acc[hf][it][pt] = MFMA(sfr[it], xfr[pt], acc[hf][it][pt]);
    }
  }

  const unsigned short* hp = hprev + (size_t)blockIdx.x * 8192;
  float esc[2][2];
  #pragma unroll
  for (int hf = 0; hf < 2; hf++)
    #pragma unroll
    for (int it = 0; it < 2; it++)
      esc[hf][it] = __expf(sdA[ibh[hf] + it * 16 + (l & 15)]);
  #pragma unroll
  for (int kn = 0; kn < 4; kn++){
    bf16x8 hfr[4];
    #pragma unroll
    for (int pt = 0; pt < 4; pt++){
      int p = pt * 16 + (l & 15);
      int n = kn * 32 + ((l >> 4) << 3);
      hfr[pt] = *(const bf16x8*)(hp + p * 128 + n);
    }
    #pragma unroll
    for (int hf = 0; hf < 2; hf++)
      #pragma unroll
      for (int it = 0; it < 2; it++){
        bf16x8 afv;
        #pragma unroll
        for (int e = 0; e < 8; e++)
          afv[e] = (short)f2bf(bf2f((unsigned short)cfr[hf][it][kn][e]) * esc[hf][it]);
        #pragma unroll
        for (int pt = 0; pt < 4; pt++)
          acc[hf][it][pt] = MFMA(afv, hfr[pt], acc[hf][it][pt]);
      }
  }

  float dph = Dp[h];
  #pragma unroll
  for (int hf = 0; hf < 2; hf++)
    #pragma unroll
    for (int it = 0; it < 2; it++)
      #pragma unroll
      for (int pt = 0; pt < 4; pt++)
        #pragma unroll
        for (int r = 0; r < 4; r++){
          int i = ibh[hf] + it * 16 + ((l >> 4) << 2) + r;
          int p = pt * 16 + (l & 15);
          float xv = bf2f(sxT[p][i]);
          float v = acc[hf][it][pt][r] + dph * xv;
          y[(size_t)(tok0 + i) * 4096 + h * 64 + p] = f2bf(v);
        }
}

// ---------- gate with silu(z), RMS-norm, * norm_w -> bf16 ----------
__global__ __launch_bounds__(256) void k_norm(const unsigned short* __restrict__ y,
                                              const unsigned short* __restrict__ zbuf,
                                              const float* __restrict__ norm_w,
                                              unsigned short* __restrict__ yn){
  int tok = blockIdx.x, t = threadIdx.x, w = t >> 6, l = t & 63;
  float vals[16];
  float ss = 0.f;
  #pragma unroll
  for (int q = 0; q < 2; q++){
    int col = q * 2048 + t * 8;
    bf16x8 yv = *(const bf16x8*)(y    + (size_t)tok * 4096 + col);
    bf16x8 zv = *(const bf16x8*)(zbuf + (size_t)tok * 4096 + col);
    #pragma unroll
    for (int e = 0; e < 8; e++){
      float yy = bf2f((unsigned short)yv[e]);
      float zz = bf2f((unsigned short)zv[e]);
      float g = yy * (zz / (1.f + __expf(-zz)));
      vals[q * 8 + e] = g;
      ss += g * g;
    }
  }
  #pragma unroll
  for (int off = 32; off >= 1; off >>= 1) ss += __shfl_xor(ss, off, 64);
  __shared__ float red[4];
  if (l == 0) red[w] = ss;
  __syncthreads();
  float total = red[0] + red[1] + red[2] + red[3];
  float scale = rsqrtf(total * (1.f / 4096.f) + 1e-5f);
  #pragma unroll
  for (int q = 0; q < 2; q++){
    int col = q * 2048 + t * 8;
    bf16x8 ov;
    #pragma unroll
    for (int e = 0; e < 8; e++) ov[e] = (short)f2bf(vals[q * 8 + e] * scale * norm_w[col + e]);
    *(bf16x8*)(yn + (size_t)tok * 4096 + col) = ov;
  }
}

extern "C" void kernel_launch(void* const* d_in, const int* in_sizes, int n_in,
                              void* d_out, int out_size, void* d_ws, size_t ws_size,
                              hipStream_t stream) {
  const float* u       = (const float*)d_in[0];
  const float* W_in    = (const float*)d_in[1];
  const float* conv_w  = (const float*)d_in[2];
  const float* conv_b  = (const float*)d_in[3];
  const float* dt_bias = (const float*)d_in[4];
  const float* A_log   = (const float*)d_in[5];
  const float* Dp      = (const float*)d_in[6];
  const float* norm_w  = (const float*)d_in[7];
  const float* W_out   = (const float*)d_in[8];

  char* ws = (char*)d_ws;
  size_t off = 0;
  auto nxt = [&](size_t bytes) -> char* {
    char* r = ws + off;
    off += (bytes + 255) & ~(size_t)255;
    return r;
  };
  char* RZ = nxt(4096ull * 4096 * 2);   // zbuf -> wout_bf
  char* RX = nxt(4096ull * 4352 * 2);   // xbc -> states(f32) -> ybuf
  char* RC = nxt(4096ull * 4352 * 2);   // win_bf -> xc -> ynbuf
  char* RH = nxt(1024ull * 8192 * 2);   // u_bf -> hprev
  float* dtw  = (float*)nxt(4096ull * 64 * 4);
  float* cdec = (float*)nxt(1024ull * 4);
  size_t need = off;
  (void)in_sizes; (void)n_in; (void)out_size;
  if (ws_size < need) return;

  unsigned short* zbuf    = (unsigned short*)RZ;
  unsigned short* wout_bf = (unsigned short*)RZ;   // after k_norm
  unsigned short* xbc     = (unsigned short*)RX;
  float*          states  = (float*)RX;
  unsigned short* ybuf    = (unsigned short*)RX;
  unsigned short* win_bf  = (unsigned short*)RC;
  unsigned short* xc      = (unsigned short*)RC;
  unsigned short* ynbuf   = (unsigned short*)RC;
  unsigned short* u_bf    = (unsigned short*)RH;
  unsigned short* hprev   = (unsigned short*)RH;

  k_f2bf<<<8192,  256, 0, stream>>>(u,    u_bf,   4096 * 2048);
  k_f2bf<<<17024, 256, 0, stream>>>(W_in, win_bf, 8512 * 2048);
  k_dtg<<<64, 256, 0, stream>>>(u_bf, win_bf, dt_bias, dtw);
  // in-proj: M=4096, N=8448, K=2048; 256x256 tiles, grid 33x16
  k_gcnt<256,1><<<dim3(33, 16), 512, 0, stream>>>(u_bf, win_bf, zbuf, xbc, 8448, 2048);
  k_conv<<<8704, 256, 0, stream>>>(xbc, conv_w, conv_b, xc);
  k_states<<<1024, 256, 0, stream>>>(xc, dtw, A_log, states, cdec);
  k_scan<<<512, 256, 0, stream>>>(states, cdec, hprev);
  k_y<<<1024, 256, 0, stream>>>(xc, dtw, A_log, hprev, Dp, ybuf);
  k_norm<<<4096, 256, 0, stream>>>(ybuf, zbuf, norm_w, ynbuf);
  k_f2bf<<<8192, 256, 0, stream>>>(W_out, wout_bf, 2048 * 4096);
  // out-proj: M=4096, N=2048, K=4096; 128x256 tiles, grid 8x32 (256 blocks)
  k_gcnt<128,0><<<dim3(8, 32), 512, 0, stream>>>(ynbuf, wout_bf, d_out, nullptr, 2048, 4096);
}